// Round 12
// baseline (211.707 us; speedup 1.0000x reference)
//
#include <hip/hip_runtime.h>
#include <math.h>

#define BATCH 2
#define SEQ 2048
#define NX 1024
#define NSTATE 1024
#define NHEAD 16
#define HDIM 64
#define QKV_LD (3*NSTATE)

typedef __attribute__((ext_vector_type(4))) float f32x4;
typedef __attribute__((ext_vector_type(8))) short bf16x8;

__device__ __forceinline__ unsigned short f2bf(float x) {
    unsigned int u = __float_as_uint(x);
    u = (u + 0x7FFFu + ((u >> 16) & 1u)) >> 16;
    return (unsigned short)u;
}

__device__ __forceinline__ unsigned int cvtpk_bf16(float a, float b) {
    unsigned int r;
    asm("v_cvt_pk_bf16_f32 %0, %1, %2" : "=v"(r) : "v"(a), "v"(b));
    return r;
}

#define GLL(src, dst) __builtin_amdgcn_global_load_lds( \
    (const __attribute__((address_space(1))) void*)(src), \
    (__attribute__((address_space(3))) void*)(dst), 16, 0, 0)

// Fused prep: [0,4096) cast x -> bf16; [4096,4864) transpose-cast w_c;
// [4864,5120) transpose-cast w_p.
__global__ __launch_bounds__(256) void prep_kernel(
    const float* __restrict__ x, const float* __restrict__ w_c,
    const float* __restrict__ w_p,
    unsigned short* __restrict__ xbf, unsigned short* __restrict__ wcT,
    unsigned short* __restrict__ wpT)
{
    const int bx = blockIdx.x;
    const int t = threadIdx.x;
    if (bx < 4096) {
        int i = bx * 256 + t;
        float4 v = ((const float4*)x)[i];
        ushort4 o;
        o.x = f2bf(v.x); o.y = f2bf(v.y); o.z = f2bf(v.z); o.w = f2bf(v.w);
        ((ushort4*)xbf)[i] = o;
        return;
    }
    __shared__ float tile[64][65];
    const float* in;
    unsigned short* out;
    int R, C, c0, r0;
    if (bx < 4096 + 768) {
        int idx = bx - 4096;
        in = w_c; out = wcT; R = NX; C = 3 * NSTATE;
        c0 = (idx % 48) * 64; r0 = (idx / 48) * 64;
    } else {
        int idx = bx - 4864;
        in = w_p; out = wpT; R = NX; C = NSTATE;
        c0 = (idx % 16) * 64; r0 = (idx / 16) * 64;
    }
    const int cc = t & 63;
    const int rb = t >> 6;
    #pragma unroll
    for (int i = 0; i < 16; i++) {
        int rr = rb + i * 4;
        tile[rr][cc] = in[(size_t)(r0 + rr) * C + c0 + cc];
    }
    __syncthreads();
    #pragma unroll
    for (int i = 0; i < 16; i++) {
        int rr = rb + i * 4;
        out[(size_t)(c0 + rr) * R + r0 + cc] = f2bf(tile[cc][rr]);
    }
}

// C[M,N] = A[M,K](bf16) @ BT[N,K]^T(bf16) + bias. 128x128 tile, 1D grid with
// bijective XCD-region swizzle. If WVT and the block is in the V column range
// (col >= 2*NSTATE), write TRANSPOSED into vt[(b*16+h)*64+d][s] instead of C.
template<int RX, int RY, int NBX, bool BF16_OUT, bool WVT>
__global__ __launch_bounds__(256) void gemm_bf16(
    const unsigned short* __restrict__ A,
    const unsigned short* __restrict__ BT,
    const float* __restrict__ bias,
    void* __restrict__ Cv, unsigned short* __restrict__ vtout,
    int M, int N, int K)
{
    const int flat = blockIdx.x;
    const int xcd = flat & 7;
    const int j = flat >> 3;
    const int bx = (xcd % (NBX / RX)) * RX + (j % RX);
    const int by = (xcd / (NBX / RX)) * RY + (j / RX);

    __shared__ unsigned short Als[128 * 32];
    __shared__ unsigned short Bls[128 * 32];
    const int tid = threadIdx.x;
    const int wave = tid >> 6, lane = tid & 63;
    const int bm = bx * 128, bn = by * 128;
    const int wr = (wave >> 1) * 64, wc = (wave & 1) * 64;

    f32x4 acc[4][4];
    #pragma unroll
    for (int m = 0; m < 4; m++)
        #pragma unroll
        for (int n = 0; n < 4; n++)
            acc[m][n] = (f32x4){0.f, 0.f, 0.f, 0.f};

    const int arow = tid >> 2;
    const int ac8 = (tid & 3) * 8;
    char* alds0 = (char*)Als + wave * 1024;
    char* blds0 = (char*)Bls + wave * 1024;
    const int fr = lane & 15, kq = (lane >> 4) * 8;

    for (int k0 = 0; k0 < K; k0 += 32) {
        const unsigned short* ga0 = A  + (size_t)(bm + arow) * K + k0 + ac8;
        const unsigned short* gb0 = BT + (size_t)(bn + arow) * K + k0 + ac8;
        GLL(ga0, alds0);
        GLL(ga0 + (size_t)64 * K, alds0 + 4096);
        GLL(gb0, blds0);
        GLL(gb0 + (size_t)64 * K, blds0 + 4096);
        __syncthreads();

        bf16x8 af[4], bfr[4];
        #pragma unroll
        for (int m = 0; m < 4; m++)
            af[m] = *(const bf16x8*)&Als[(wr + m * 16 + fr) * 32 + kq];
        #pragma unroll
        for (int n = 0; n < 4; n++)
            bfr[n] = *(const bf16x8*)&Bls[(wc + n * 16 + fr) * 32 + kq];
        #pragma unroll
        for (int m = 0; m < 4; m++)
            #pragma unroll
            for (int n = 0; n < 4; n++)
                acc[m][n] = __builtin_amdgcn_mfma_f32_16x16x32_bf16(
                    af[m], bfr[n], acc[m][n], 0, 0, 0);
        __syncthreads();
    }

    const int cr = (lane >> 4) * 4;
    const int ccol = lane & 15;
    if (WVT && bn >= 2 * NSTATE) {
        // V block: write transposed to vt. Per (m,n): 4 consecutive s at one d.
        #pragma unroll
        for (int m = 0; m < 4; m++) {
            const int row0 = bm + wr + m * 16 + cr;      // s global, mult of 4
            const int bb = row0 >> 11;                   // batch
            const int sl = row0 & 2047;                  // s local
            #pragma unroll
            for (int n = 0; n < 4; n++) {
                const int col = bn + wc + n * 16 + ccol;
                const float bv = bias[col];
                const int vcol = col - 2 * NSTATE;       // 0..1023
                unsigned short o4[4];
                #pragma unroll
                for (int j2 = 0; j2 < 4; j2++)
                    o4[j2] = f2bf(acc[m][n][j2] + bv);
                // vt[(bb*16 + h)*64 + d][sl..sl+3], h=vcol>>6, d=vcol&63
                unsigned short* dst = vtout +
                    ((size_t)(bb * 16 + (vcol >> 6)) * 64 + (vcol & 63)) * SEQ + sl;
                *(uint2*)dst = *(const uint2*)o4;
            }
        }
        return;
    }
    #pragma unroll
    for (int m = 0; m < 4; m++) {
        const int row = bm + wr + m * 16 + cr;
        #pragma unroll
        for (int n = 0; n < 4; n++) {
            const int col = bn + wc + n * 16 + ccol;
            const float bv = bias[col];
            #pragma unroll
            for (int j2 = 0; j2 < 4; j2++) {
                float v = acc[m][n][j2] + bv;
                if (BF16_OUT)
                    ((unsigned short*)Cv)[(size_t)(row + j2) * N + col] = f2bf(v);
                else
                    ((float*)Cv)[(size_t)(row + j2) * N + col] = v;
            }
        }
    }
}

// Small-tile GEMM: 64x64 tile, 4 waves each 32x32 (2x2 acc). 1D XCD swizzle.
template<int RX, int RY, int NBX, bool BF16_OUT>
__global__ __launch_bounds__(256) void gemm_bf16_s(
    const unsigned short* __restrict__ A,
    const unsigned short* __restrict__ BT,
    const float* __restrict__ bias,
    void* __restrict__ Cv, int M, int N, int K)
{
    const int flat = blockIdx.x;
    const int xcd = flat & 7;
    const int j = flat >> 3;
    const int bx = (xcd % (NBX / RX)) * RX + (j % RX);
    const int by = (xcd / (NBX / RX)) * RY + (j / RX);

    __shared__ unsigned short Als[64 * 32];
    __shared__ unsigned short Bls[64 * 32];
    const int tid = threadIdx.x;
    const int wave = tid >> 6, lane = tid & 63;
    const int bm = bx * 64, bn = by * 64;
    const int wr = (wave >> 1) * 32, wc = (wave & 1) * 32;

    f32x4 acc[2][2];
    #pragma unroll
    for (int m = 0; m < 2; m++)
        #pragma unroll
        for (int n = 0; n < 2; n++)
            acc[m][n] = (f32x4){0.f, 0.f, 0.f, 0.f};

    const int arow = tid >> 2;
    const int ac8 = (tid & 3) * 8;
    char* alds = (char*)Als + tid * 16;
    char* blds = (char*)Bls + tid * 16;
    const int fr = lane & 15, kq = (lane >> 4) * 8;

    for (int k0 = 0; k0 < K; k0 += 32) {
        GLL(A  + (size_t)(bm + arow) * K + k0 + ac8, alds);
        GLL(BT + (size_t)(bn + arow) * K + k0 + ac8, blds);
        __syncthreads();

        bf16x8 af[2], bfr[2];
        #pragma unroll
        for (int m = 0; m < 2; m++)
            af[m] = *(const bf16x8*)&Als[(wr + m * 16 + fr) * 32 + kq];
        #pragma unroll
        for (int n = 0; n < 2; n++)
            bfr[n] = *(const bf16x8*)&Bls[(wc + n * 16 + fr) * 32 + kq];
        #pragma unroll
        for (int m = 0; m < 2; m++)
            #pragma unroll
            for (int n = 0; n < 2; n++)
                acc[m][n] = __builtin_amdgcn_mfma_f32_16x16x32_bf16(
                    af[m], bfr[n], acc[m][n], 0, 0, 0);
        __syncthreads();
    }

    const int cr = (lane >> 4) * 4;
    const int ccol = lane & 15;
    #pragma unroll
    for (int m = 0; m < 2; m++) {
        const int row = bm + wr + m * 16 + cr;
        #pragma unroll
        for (int n = 0; n < 2; n++) {
            const int col = bn + wc + n * 16 + ccol;
            const float bv = bias[col];
            #pragma unroll
            for (int j2 = 0; j2 < 4; j2++) {
                float v = acc[m][n][j2] + bv;
                if (BF16_OUT)
                    ((unsigned short*)Cv)[(size_t)(row + j2) * N + col] = f2bf(v);
                else
                    ((float*)Cv)[(size_t)(row + j2) * N + col] = v;
            }
        }
    }
}

// MFMA flash attention v12: dual q-tile per block. Block bx owns q-tiles
// qbA=31-bx and qbB=bx; one K/V staging stream serves both (B range subset
// of A). Per block exactly 33 tile-activations -> perfect balance. 4 waves
// x 16 q-rows per group; dbuf staging, one barrier/tile. grid (16, H, B).
__global__ __launch_bounds__(256) void attn_mfma(
    const unsigned short* __restrict__ qkv,
    const unsigned short* __restrict__ vt,
    unsigned short* __restrict__ a_out)
{
    const int bx = blockIdx.x;
    const int qbA = 31 - bx, qbB = bx;
    const int h = blockIdx.y, b = blockIdx.z;
    const int tid = threadIdx.x;
    const int w = tid >> 6, lane = tid & 63;
    const int c = lane & 15, hh = lane >> 4;

    __shared__ unsigned short Kls[2 * 64 * 64];
    __shared__ unsigned short Vls[2 * 64 * 64];
    __shared__ unsigned short Pls[4][16 * 64];

    const float Cc = 0.18033688f;          // 0.125 * log2(e)

    // staging geometry
    const int o0 = tid * 16;
    const int r0 = o0 >> 7, sc0 = (o0 & 127) ^ ((r0 & 7) << 4);
    const int o1 = 4096 + tid * 16;
    const int r1 = o1 >> 7, sc1 = (o1 & 127) ^ ((r1 & 7) << 4);

    char* kld = (char*)Kls + w * 1024;
    char* vld = (char*)Vls + w * 1024;
    const char* gkbase = (const char*)(qkv + (size_t)b * SEQ * QKV_LD + NSTATE + h * HDIM);
    const char* gvbase = (const char*)(vt + (size_t)(b * NHEAD + h) * HDIM * SEQ);

    #define STAGE(kt_, buf_) do { \
        const char* gk = gkbase + (size_t)(kt_) * 64 * 6144; \
        const char* gv = gvbase + (size_t)(kt_) * 128; \
        char* kd = kld + (buf_) * 8192; \
        char* vd = vld + (buf_) * 8192; \
        GLL(gk + (size_t)r0 * 6144 + sc0, kd); \
        GLL(gk + (size_t)r1 * 6144 + sc1, kd + 4096); \
        GLL(gv + (size_t)r0 * 4096 + sc0, vd); \
        GLL(gv + (size_t)r1 * 4096 + sc1, vd + 4096); \
    } while (0)

    // Q fragments for both groups
    const unsigned short* qpA = qkv + (size_t)(b * SEQ + qbA * 64 + w * 16 + c) * QKV_LD + h * HDIM;
    bf16x8 qfA0 = *(const bf16x8*)(qpA + hh * 8);
    bf16x8 qfA1 = *(const bf16x8*)(qpA + 32 + hh * 8);
    const unsigned short* qpB = qkv + (size_t)(b * SEQ + qbB * 64 + w * 16 + c) * QKV_LD + h * HDIM;
    bf16x8 qfB0 = *(const bf16x8*)(qpB + hh * 8);
    bf16x8 qfB1 = *(const bf16x8*)(qpB + 32 + hh * 8);

    f32x4 accA[4], accB[4];
    #pragma unroll
    for (int n = 0; n < 4; n++) {
        accA[n] = (f32x4){0.f, 0.f, 0.f, 0.f};
        accB[n] = (f32x4){0.f, 0.f, 0.f, 0.f};
    }
    float mA = -1e30f, lA = 0.f, mB = -1e30f, lB = 0.f;

    const int nkt = qbA + 1;
    STAGE(0, 0);
    __syncthreads();

    for (int kt = 0; kt < nkt; kt++) {
        const int cur = kt & 1;
        if (kt + 1 < nkt) STAGE(kt + 1, cur ^ 1);

        const char* kb = (const char*)Kls + cur * 8192;
        const char* vb = (const char*)Vls + cur * 8192;
        const bool doB = (kt <= qbB);

        // K fragments once, both QK^T groups
        f32x4 saccA[4], saccB[4];
        __builtin_amdgcn_s_setprio(1);
        #pragma unroll
        for (int m = 0; m < 4; m++) {
            const int row = m * 16 + c;
            const int sw = (row & 7) << 4;
            bf16x8 kf0 = *(const bf16x8*)(kb + row * 128 + ((hh * 16) ^ sw));
            bf16x8 kf1 = *(const bf16x8*)(kb + row * 128 + ((64 + hh * 16) ^ sw));
            f32x4 z = (f32x4){0.f, 0.f, 0.f, 0.f};
            z = __builtin_amdgcn_mfma_f32_16x16x32_bf16(kf0, qfA0, z, 0, 0, 0);
            saccA[m] = __builtin_amdgcn_mfma_f32_16x16x32_bf16(kf1, qfA1, z, 0, 0, 0);
            if (doB) {
                f32x4 z2 = (f32x4){0.f, 0.f, 0.f, 0.f};
                z2 = __builtin_amdgcn_mfma_f32_16x16x32_bf16(kf0, qfB0, z2, 0, 0, 0);
                saccB[m] = __builtin_amdgcn_mfma_f32_16x16x32_bf16(kf1, qfB1, z2, 0, 0, 0);
            }
        }
        __builtin_amdgcn_s_setprio(0);

        // ---- group A softmax + PV ----
        {
            const bool diag = (kt == qbA);
            float s[16];
            #pragma unroll
            for (int m = 0; m < 4; m++)
                #pragma unroll
                for (int j = 0; j < 4; j++) {
                    float sv = saccA[m][j];
                    if (diag) {
                        int klocal = m * 16 + hh * 4 + j;
                        if (klocal > w * 16 + c) sv = -1e30f;
                    }
                    s[m * 4 + j] = sv;
                }
            float x0 = fmaxf(s[0], s[1]),  x1 = fmaxf(s[2], s[3]);
            float x2 = fmaxf(s[4], s[5]),  x3 = fmaxf(s[6], s[7]);
            float x4 = fmaxf(s[8], s[9]),  x5 = fmaxf(s[10], s[11]);
            float x6 = fmaxf(s[12], s[13]), x7 = fmaxf(s[14], s[15]);
            float pmax = fmaxf(fmaxf(fmaxf(x0, x1), fmaxf(x2, x3)),
                               fmaxf(fmaxf(x4, x5), fmaxf(x6, x7)));
            pmax = fmaxf(pmax, __shfl_xor(pmax, 16));
            pmax = fmaxf(pmax, __shfl_xor(pmax, 32));
            if (!__all(pmax <= mA + 64.0f)) {
                const float mnew = fmaxf(mA, pmax);
                const float alpha = exp2f((mA - mnew) * Cc);
                mA = mnew;
                lA *= alpha;
                const float a0 = __shfl(alpha, hh * 4 + 0);
                const float a1 = __shfl(alpha, hh * 4 + 1);
                const float a2 = __shfl(alpha, hh * 4 + 2);
                const float a3 = __shfl(alpha, hh * 4 + 3);
                #pragma unroll
                for (int n = 0; n < 4; n++) {
                    accA[n][0] *= a0; accA[n][1] *= a1;
                    accA[n][2] *= a2; accA[n][3] *= a3;
                }
            }
            const float mc = mA * Cc;
            float p[16];
            #pragma unroll
            for (int i = 0; i < 16; i++)
                p[i] = exp2f(fmaf(s[i], Cc, -mc));
            {
                float a0 = p[0] + p[1],  a1 = p[2] + p[3];
                float a2 = p[4] + p[5],  a3 = p[6] + p[7];
                float a4 = p[8] + p[9],  a5 = p[10] + p[11];
                float a6 = p[12] + p[13], a7 = p[14] + p[15];
                lA += ((a0 + a1) + (a2 + a3)) + ((a4 + a5) + (a6 + a7));
            }
            char* pb = (char*)&Pls[w][0] + c * 128;
            const int swp = (c & 7) << 4;
            #pragma unroll
            for (int m = 0; m < 4; m++) {
                uint2 u2;
                u2.x = cvtpk_bf16(p[m * 4 + 0], p[m * 4 + 1]);
                u2.y = cvtpk_bf16(p[m * 4 + 2], p[m * 4 + 3]);
                *(uint2*)(pb + ((m * 32 + hh * 8) ^ swp)) = u2;
            }
            bf16x8 pf0 = *(const bf16x8*)(pb + ((hh * 16) ^ swp));
            bf16x8 pf1 = *(const bf16x8*)(pb + ((64 + hh * 16) ^ swp));
            __builtin_amdgcn_s_setprio(1);
            #pragma unroll
            for (int n = 0; n < 4; n++) {
                const int row = n * 16 + c;
                const int sw = (row & 7) << 4;
                bf16x8 vf0 = *(const bf16x8*)(vb + row * 128 + ((hh * 16) ^ sw));
                bf16x8 vf1 = *(const bf16x8*)(vb + row * 128 + ((64 + hh * 16) ^ sw));
                accA[n] = __builtin_amdgcn_mfma_f32_16x16x32_bf16(pf0, vf0, accA[n], 0, 0, 0);
                accA[n] = __builtin_amdgcn_mfma_f32_16x16x32_bf16(pf1, vf1, accA[n], 0, 0, 0);
            }
            __builtin_amdgcn_s_setprio(0);
        }

        // ---- group B softmax + PV (while active) ----
        if (doB) {
            const bool diag = (kt == qbB);
            float s[16];
            #pragma unroll
            for (int m = 0; m < 4; m++)
                #pragma unroll
                for (int j = 0; j < 4; j++) {
                    float sv = saccB[m][j];
                    if (diag) {
                        int klocal = m * 16 + hh * 4 + j;
                        if (klocal > w * 16 + c) sv = -1e30f;
                    }
                    s[m * 4 + j] = sv;
                }
            float x0 = fmaxf(s[0], s[1]),  x1 = fmaxf(s[2], s[3]);
            float x2 = fmaxf(s[4], s[5]),  x3 = fmaxf(s[6], s[7]);
            float x4 = fmaxf(s[8], s[9]),  x5 = fmaxf(s[10], s[11]);
            float x6 = fmaxf(s[12], s[13]), x7 = fmaxf(s[14], s[15]);
            float pmax = fmaxf(fmaxf(fmaxf(x0, x1), fmaxf(x2, x3)),
                               fmaxf(fmaxf(x4, x5), fmaxf(x6, x7)));
            pmax = fmaxf(pmax, __shfl_xor(pmax, 16));
            pmax = fmaxf(pmax, __shfl_xor(pmax, 32));
            if (!__all(pmax <= mB + 64.0f)) {
                const float mnew = fmaxf(mB, pmax);
                const float alpha = exp2f((mB - mnew) * Cc);
                mB = mnew;
                lB *= alpha;
                const float a0 = __shfl(alpha, hh * 4 + 0);
                const float a1 = __shfl(alpha, hh * 4 + 1);
                const float a2 = __shfl(alpha, hh * 4 + 2);
                const float a3 = __shfl(alpha, hh * 4 + 3);
                #pragma unroll
                for (int n = 0; n < 4; n++) {
                    accB[n][0] *= a0; accB[n][1] *= a1;
                    accB[n][2] *= a2; accB[n][3] *= a3;
                }
            }
            const float mc = mB * Cc;
            float p[16];
            #pragma unroll
            for (int i = 0; i < 16; i++)
                p[i] = exp2f(fmaf(s[i], Cc, -mc));
            {
                float a0 = p[0] + p[1],  a1 = p[2] + p[3];
                float a2 = p[4] + p[5],  a3 = p[6] + p[7];
                float a4 = p[8] + p[9],  a5 = p[10] + p[11];
                float a6 = p[12] + p[13], a7 = p[14] + p[15];
                lB += ((a0 + a1) + (a2 + a3)) + ((a4 + a5) + (a6 + a7));
            }
            char* pb = (char*)&Pls[w][0] + c * 128;
            const int swp = (c & 7) << 4;
            #pragma unroll
            for (int m = 0; m < 4; m++) {
                uint2 u2;
                u2.x = cvtpk_bf16(p[m * 4 + 0], p[m * 4 + 1]);
                u2.y = cvtpk_bf16(p[m * 4 + 2], p[m * 4 + 3]);
                *(uint2*)(pb + ((m * 32 + hh * 8) ^ swp)) = u2;
            }
            bf16x8 pf0 = *(const bf16x8*)(pb + ((hh * 16) ^ swp));
            bf16x8 pf1 = *(const bf16x8*)(pb + ((64 + hh * 16) ^ swp));
            __builtin_amdgcn_s_setprio(1);
            #pragma unroll
            for (int n = 0; n < 4; n++) {
                const int row = n * 16 + c;
                const int sw = (row & 7) << 4;
                bf16x8 vf0 = *(const bf16x8*)(vb + row * 128 + ((hh * 16) ^ sw));
                bf16x8 vf1 = *(const bf16x8*)(vb + row * 128 + ((64 + hh * 16) ^ sw));
                accB[n] = __builtin_amdgcn_mfma_f32_16x16x32_bf16(pf0, vf0, accB[n], 0, 0, 0);
                accB[n] = __builtin_amdgcn_mfma_f32_16x16x32_bf16(pf1, vf1, accB[n], 0, 0, 0);
            }
            __builtin_amdgcn_s_setprio(0);
        }
        __syncthreads();
    }
    #undef STAGE

    // finalize + store both groups
    #pragma unroll
    for (int gsel = 0; gsel < 2; gsel++) {
        const int qb = gsel ? qbB : qbA;
        f32x4* acc = gsel ? accB : accA;
        float l = gsel ? lB : lA;
        l += __shfl_xor(l, 16);
        l += __shfl_xor(l, 32);
        const float linv = 1.f / l;
        const float li0 = __shfl(linv, hh * 4 + 0);
        const float li1 = __shfl(linv, hh * 4 + 1);
        const float li2 = __shfl(linv, hh * 4 + 2);
        const float li3 = __shfl(linv, hh * 4 + 3);
        const size_t orow0 = (size_t)(b * SEQ + qb * 64 + w * 16 + hh * 4);
        #pragma unroll
        for (int n = 0; n < 4; n++) {
            const int col = h * HDIM + n * 16 + c;
            a_out[(orow0 + 0) * NSTATE + col] = f2bf(acc[n][0] * li0);
            a_out[(orow0 + 1) * NSTATE + col] = f2bf(acc[n][1] * li1);
            a_out[(orow0 + 2) * NSTATE + col] = f2bf(acc[n][2] * li2);
            a_out[(orow0 + 3) * NSTATE + col] = f2bf(acc[n][3] * li3);
        }
    }
}

extern "C" void kernel_launch(void* const* d_in, const int* in_sizes, int n_in,
                              void* d_out, int out_size, void* d_ws, size_t ws_size,
                              hipStream_t stream)
{
    const float* x   = (const float*)d_in[0];
    const float* w_c = (const float*)d_in[1];
    const float* b_c = (const float*)d_in[2];
    const float* w_p = (const float*)d_in[3];
    const float* b_p = (const float*)d_in[4];
    float* out = (float*)d_out;

    const int M = BATCH * SEQ;   // 4096

    char* ws = (char*)d_ws;
    unsigned short* qkvbf = (unsigned short*)ws;                          // 25165824 B (V region unused)
    unsigned short* vt    = (unsigned short*)(ws + 25165824);             //  8388608 B
    unsigned short* xbf   = (unsigned short*)(ws + 25165824 + 8388608);   //  8388608 B (reused as attn_out)
    unsigned short* wcT   = (unsigned short*)(ws + 25165824 + 2*8388608); //  6291456 B
    unsigned short* wpT   = (unsigned short*)(ws + 25165824 + 2*8388608 + 6291456); // 2097152 B

    // fused prep: cast x + transpose-cast w_c, w_p
    prep_kernel<<<5120, 256, 0, stream>>>(x, w_c, w_p, xbf, wcT, wpT);

    // 1) QKV projection -> bf16 qkv (Q,K row-major; V written transposed to vt)
    gemm_bf16<8, 12, 32, true, true><<<768, 256, 0, stream>>>(
        xbf, wcT, b_c, qkvbf, vt, M, 3 * NSTATE, NX);

    // 2) MFMA flash attention (dual q-tile blocks, uniform 33 activations)
    attn_mfma<<<dim3(16, NHEAD, BATCH), 256, 0, stream>>>(qkvbf, vt, xbf);

    // 3) output projection -> fp32 d_out (64x64 tiles, 1024 blocks)
    gemm_bf16_s<16, 8, 64, false><<<1024, 256, 0, stream>>>(
        xbf, wpT, b_p, out, M, NSTATE, NX);
}

// Round 13
// 195.322 us; speedup vs baseline: 1.0839x; 1.0839x over previous
//
#include <hip/hip_runtime.h>
#include <math.h>

#define BATCH 2
#define SEQ 2048
#define NX 1024
#define NSTATE 1024
#define NHEAD 16
#define HDIM 64
#define QKV_LD (3*NSTATE)

typedef __attribute__((ext_vector_type(4))) float f32x4;
typedef __attribute__((ext_vector_type(8))) short bf16x8;

__device__ __forceinline__ unsigned short f2bf(float x) {
    unsigned int u = __float_as_uint(x);
    u = (u + 0x7FFFu + ((u >> 16) & 1u)) >> 16;
    return (unsigned short)u;
}

__device__ __forceinline__ unsigned int cvtpk_bf16(float a, float b) {
    unsigned int r;
    asm("v_cvt_pk_bf16_f32 %0, %1, %2" : "=v"(r) : "v"(a), "v"(b));
    return r;
}

#define GLL(src, dst) __builtin_amdgcn_global_load_lds( \
    (const __attribute__((address_space(1))) void*)(src), \
    (__attribute__((address_space(3))) void*)(dst), 16, 0, 0)

// Fused prep: [0,4096) cast x -> bf16; [4096,4864) transpose-cast w_c;
// [4864,5120) transpose-cast w_p.
__global__ __launch_bounds__(256) void prep_kernel(
    const float* __restrict__ x, const float* __restrict__ w_c,
    const float* __restrict__ w_p,
    unsigned short* __restrict__ xbf, unsigned short* __restrict__ wcT,
    unsigned short* __restrict__ wpT)
{
    const int bx = blockIdx.x;
    const int t = threadIdx.x;
    if (bx < 4096) {
        int i = bx * 256 + t;
        float4 v = ((const float4*)x)[i];
        ushort4 o;
        o.x = f2bf(v.x); o.y = f2bf(v.y); o.z = f2bf(v.z); o.w = f2bf(v.w);
        ((ushort4*)xbf)[i] = o;
        return;
    }
    __shared__ float tile[64][65];
    const float* in;
    unsigned short* out;
    int R, C, c0, r0;
    if (bx < 4096 + 768) {
        int idx = bx - 4096;
        in = w_c; out = wcT; R = NX; C = 3 * NSTATE;
        c0 = (idx % 48) * 64; r0 = (idx / 48) * 64;
    } else {
        int idx = bx - 4864;
        in = w_p; out = wpT; R = NX; C = NSTATE;
        c0 = (idx % 16) * 64; r0 = (idx / 16) * 64;
    }
    const int cc = t & 63;
    const int rb = t >> 6;
    #pragma unroll
    for (int i = 0; i < 16; i++) {
        int rr = rb + i * 4;
        tile[rr][cc] = in[(size_t)(r0 + rr) * C + c0 + cc];
    }
    __syncthreads();
    #pragma unroll
    for (int i = 0; i < 16; i++) {
        int rr = rb + i * 4;
        out[(size_t)(c0 + rr) * R + r0 + cc] = f2bf(tile[cc][rr]);
    }
}

// V-part of qkv (bf16) -> vt[(b*16+h)*64+d][s]  (bf16)
__global__ __launch_bounds__(256) void vtrans_kernel(
    const unsigned short* __restrict__ qkv, unsigned short* __restrict__ vt)
{
    __shared__ unsigned short t[64][72];
    const int s0 = blockIdx.x * 64;
    const int bh = blockIdx.y;
    const int b = bh >> 4, h = bh & 15;
    const int r = threadIdx.x >> 2;
    const int cg = (threadIdx.x & 3) * 16;
    const unsigned short* src = qkv + (size_t)(b * SEQ + s0 + r) * QKV_LD
                                + 2 * NSTATE + h * HDIM + cg;
    *(bf16x8*)&t[r][cg]     = *(const bf16x8*)src;
    *(bf16x8*)&t[r][cg + 8] = *(const bf16x8*)(src + 8);
    __syncthreads();
    unsigned short tmp[16];
    #pragma unroll
    for (int i = 0; i < 16; i++) tmp[i] = t[cg + i][r];
    unsigned short* dst = vt + (size_t)(bh * 64 + r) * SEQ + s0 + cg;
    *(bf16x8*)dst       = ((const bf16x8*)tmp)[0];
    *(bf16x8*)(dst + 8) = ((const bf16x8*)tmp)[1];
}

// C[M,N] = A[M,K](bf16) @ BT[N,K]^T(bf16) + bias. 128x128 tile, 1D grid with
// bijective XCD-region swizzle: xcd=flat&7 gets an RX x RY block region.
template<int RX, int RY, int NBX, bool BF16_OUT>
__global__ __launch_bounds__(256) void gemm_bf16(
    const unsigned short* __restrict__ A,
    const unsigned short* __restrict__ BT,
    const float* __restrict__ bias,
    void* __restrict__ Cv, int M, int N, int K)
{
    const int flat = blockIdx.x;
    const int xcd = flat & 7;
    const int j = flat >> 3;
    const int bx = (xcd % (NBX / RX)) * RX + (j % RX);
    const int by = (xcd / (NBX / RX)) * RY + (j / RX);

    __shared__ unsigned short Als[128 * 32];
    __shared__ unsigned short Bls[128 * 32];
    const int tid = threadIdx.x;
    const int wave = tid >> 6, lane = tid & 63;
    const int bm = bx * 128, bn = by * 128;
    const int wr = (wave >> 1) * 64, wc = (wave & 1) * 64;

    f32x4 acc[4][4];
    #pragma unroll
    for (int m = 0; m < 4; m++)
        #pragma unroll
        for (int n = 0; n < 4; n++)
            acc[m][n] = (f32x4){0.f, 0.f, 0.f, 0.f};

    const int arow = tid >> 2;
    const int ac8 = (tid & 3) * 8;
    char* alds0 = (char*)Als + wave * 1024;
    char* blds0 = (char*)Bls + wave * 1024;
    const int fr = lane & 15, kq = (lane >> 4) * 8;

    for (int k0 = 0; k0 < K; k0 += 32) {
        const unsigned short* ga0 = A  + (size_t)(bm + arow) * K + k0 + ac8;
        const unsigned short* gb0 = BT + (size_t)(bn + arow) * K + k0 + ac8;
        GLL(ga0, alds0);
        GLL(ga0 + (size_t)64 * K, alds0 + 4096);
        GLL(gb0, blds0);
        GLL(gb0 + (size_t)64 * K, blds0 + 4096);
        __syncthreads();

        bf16x8 af[4], bfr[4];
        #pragma unroll
        for (int m = 0; m < 4; m++)
            af[m] = *(const bf16x8*)&Als[(wr + m * 16 + fr) * 32 + kq];
        #pragma unroll
        for (int n = 0; n < 4; n++)
            bfr[n] = *(const bf16x8*)&Bls[(wc + n * 16 + fr) * 32 + kq];
        #pragma unroll
        for (int m = 0; m < 4; m++)
            #pragma unroll
            for (int n = 0; n < 4; n++)
                acc[m][n] = __builtin_amdgcn_mfma_f32_16x16x32_bf16(
                    af[m], bfr[n], acc[m][n], 0, 0, 0);
        __syncthreads();
    }

    const int cr = (lane >> 4) * 4;
    const int ccol = lane & 15;
    #pragma unroll
    for (int m = 0; m < 4; m++) {
        const int row = bm + wr + m * 16 + cr;
        #pragma unroll
        for (int n = 0; n < 4; n++) {
            const int col = bn + wc + n * 16 + ccol;
            const float bv = bias[col];
            #pragma unroll
            for (int j2 = 0; j2 < 4; j2++) {
                float v = acc[m][n][j2] + bv;
                if (BF16_OUT)
                    ((unsigned short*)Cv)[(size_t)(row + j2) * N + col] = f2bf(v);
                else
                    ((float*)Cv)[(size_t)(row + j2) * N + col] = v;
            }
        }
    }
}

// Small-tile GEMM v13: 64x64 tile, BK=64 (8 MFMA per barrier-pair, 16 k-steps).
// LDS rows are 128B -> XOR-swizzled staging/reads (same pattern as attn K).
template<int RX, int RY, int NBX, bool BF16_OUT>
__global__ __launch_bounds__(256) void gemm_bf16_s(
    const unsigned short* __restrict__ A,
    const unsigned short* __restrict__ BT,
    const float* __restrict__ bias,
    void* __restrict__ Cv, int M, int N, int K)
{
    const int flat = blockIdx.x;
    const int xcd = flat & 7;
    const int j = flat >> 3;
    const int bx = (xcd % (NBX / RX)) * RX + (j % RX);
    const int by = (xcd / (NBX / RX)) * RY + (j / RX);

    __shared__ unsigned short Als[64 * 64];   // 8KB, row = 128B, swizzled
    __shared__ unsigned short Bls[64 * 64];
    const int tid = threadIdx.x;
    const int wave = tid >> 6, lane = tid & 63;
    const int bm = bx * 64, bn = by * 64;
    const int wr = (wave >> 1) * 32, wc = (wave & 1) * 32;

    f32x4 acc[2][2];
    #pragma unroll
    for (int m = 0; m < 2; m++)
        #pragma unroll
        for (int n = 0; n < 2; n++)
            acc[m][n] = (f32x4){0.f, 0.f, 0.f, 0.f};

    // staging geometry (identical to attn K): o = tid*16 (+4096);
    // row r = o>>7; swizzled source col sc = (o&127) ^ ((r&7)<<4)
    const int o0 = tid * 16;
    const int r0 = o0 >> 7, sc0 = (o0 & 127) ^ ((r0 & 7) << 4);
    const int o1 = 4096 + tid * 16;
    const int r1 = o1 >> 7, sc1 = (o1 & 127) ^ ((r1 & 7) << 4);
    char* alds0 = (char*)Als + wave * 1024;
    char* blds0 = (char*)Bls + wave * 1024;

    const int fr = lane & 15;
    const int hh16 = (lane >> 4) * 16;     // byte offset of 8-elem fragment

    const char* gA = (const char*)(A  + (size_t)bm * K);
    const char* gB = (const char*)(BT + (size_t)bn * K);

    for (int k0 = 0; k0 < K; k0 += 64) {
        const char* ga = gA + (size_t)k0 * 2;
        const char* gb = gB + (size_t)k0 * 2;
        GLL(ga + (size_t)r0 * (K * 2) + sc0, alds0);
        GLL(ga + (size_t)r1 * (K * 2) + sc1, alds0 + 4096);
        GLL(gb + (size_t)r0 * (K * 2) + sc0, blds0);
        GLL(gb + (size_t)r1 * (K * 2) + sc1, blds0 + 4096);
        __syncthreads();

        #pragma unroll
        for (int s = 0; s < 2; s++) {
            bf16x8 af[2], bfr[2];
            #pragma unroll
            for (int m = 0; m < 2; m++) {
                const int row = wr + m * 16 + fr;
                const int sw = (row & 7) << 4;
                af[m] = *(const bf16x8*)((const char*)Als + row * 128
                                          + ((s * 64 + hh16) ^ sw));
            }
            #pragma unroll
            for (int n = 0; n < 2; n++) {
                const int row = wc + n * 16 + fr;
                const int sw = (row & 7) << 4;
                bfr[n] = *(const bf16x8*)((const char*)Bls + row * 128
                                           + ((s * 64 + hh16) ^ sw));
            }
            #pragma unroll
            for (int m = 0; m < 2; m++)
                #pragma unroll
                for (int n = 0; n < 2; n++)
                    acc[m][n] = __builtin_amdgcn_mfma_f32_16x16x32_bf16(
                        af[m], bfr[n], acc[m][n], 0, 0, 0);
        }
        __syncthreads();
    }

    const int cr = (lane >> 4) * 4;
    const int ccol = lane & 15;
    #pragma unroll
    for (int m = 0; m < 2; m++) {
        const int row = bm + wr + m * 16 + cr;
        #pragma unroll
        for (int n = 0; n < 2; n++) {
            const int col = bn + wc + n * 16 + ccol;
            const float bv = bias[col];
            #pragma unroll
            for (int j2 = 0; j2 < 4; j2++) {
                float v = acc[m][n][j2] + bv;
                if (BF16_OUT)
                    ((unsigned short*)Cv)[(size_t)(row + j2) * N + col] = f2bf(v);
                else
                    ((float*)Cv)[(size_t)(row + j2) * N + col] = v;
            }
        }
    }
}

// MFMA flash attention (r11). 4 waves x 16 q-rows = one 64-row q-tile per
// block; 1024 blocks = 4 blocks/CU. Reflected qb map balances per-CU work.
// XCD grouping via f&31 -> K/V L2-resident. Dbuf staging, one barrier/tile.
__global__ __launch_bounds__(256) void attn_mfma(
    const unsigned short* __restrict__ qkv,
    const unsigned short* __restrict__ vt,
    unsigned short* __restrict__ a_out)
{
    const int f = blockIdx.x;
    const int k_ = f >> 8;                 // 0..3
    const int u = (f >> 5) & 7;            // 0..7 (stable per CU)
    const int bh = f & 31;
    const int qb = (k_ & 1) ? (k_ * 8 + 7 - u) : (k_ * 8 + u);
    const int b = bh >> 4, h = bh & 15;
    const int tid = threadIdx.x;
    const int w = tid >> 6, lane = tid & 63;
    const int c = lane & 15, hh = lane >> 4;

    __shared__ unsigned short Kls[2 * 64 * 64];
    __shared__ unsigned short Vls[2 * 64 * 64];
    __shared__ unsigned short Pls[4][16 * 64];

    const float Cc = 0.18033688f;          // 0.125 * log2(e)

    const int o0 = tid * 16;
    const int r0 = o0 >> 7, sc0 = (o0 & 127) ^ ((r0 & 7) << 4);
    const int o1 = 4096 + tid * 16;
    const int r1 = o1 >> 7, sc1 = (o1 & 127) ^ ((r1 & 7) << 4);

    char* kld = (char*)Kls + w * 1024;
    char* vld = (char*)Vls + w * 1024;
    const char* gkbase = (const char*)(qkv + (size_t)b * SEQ * QKV_LD + NSTATE + h * HDIM);
    const char* gvbase = (const char*)(vt + (size_t)(b * NHEAD + h) * HDIM * SEQ);

    #define STAGE(kt_, buf_) do { \
        const char* gk = gkbase + (size_t)(kt_) * 64 * 6144; \
        const char* gv = gvbase + (size_t)(kt_) * 128; \
        char* kd = kld + (buf_) * 8192; \
        char* vd = vld + (buf_) * 8192; \
        GLL(gk + (size_t)r0 * 6144 + sc0, kd); \
        GLL(gk + (size_t)r1 * 6144 + sc1, kd + 4096); \
        GLL(gv + (size_t)r0 * 4096 + sc0, vd); \
        GLL(gv + (size_t)r1 * 4096 + sc1, vd + 4096); \
    } while (0)

    const size_t qrow = (size_t)(b * SEQ + qb * 64 + w * 16 + c);
    const unsigned short* qp = qkv + qrow * QKV_LD + h * HDIM;
    bf16x8 qf0 = *(const bf16x8*)(qp + hh * 8);
    bf16x8 qf1 = *(const bf16x8*)(qp + 32 + hh * 8);

    f32x4 acc_o[4];
    #pragma unroll
    for (int n = 0; n < 4; n++) acc_o[n] = (f32x4){0.f, 0.f, 0.f, 0.f};
    float m_run = -1e30f, l = 0.f;

    const int nkt = qb + 1;
    STAGE(0, 0);
    __syncthreads();

    for (int kt = 0; kt < nkt; kt++) {
        const int cur = kt & 1;
        if (kt + 1 < nkt) STAGE(kt + 1, cur ^ 1);

        const char* kb = (const char*)Kls + cur * 8192;
        const char* vb = (const char*)Vls + cur * 8192;

        // QK^T (swapped): sacc[m] cols=q(c), rows=keys m*16 + hh*4 + j
        f32x4 sacc[4];
        __builtin_amdgcn_s_setprio(1);
        #pragma unroll
        for (int m = 0; m < 4; m++) {
            const int row = m * 16 + c;
            const int sw = (row & 7) << 4;
            bf16x8 kf0 = *(const bf16x8*)(kb + row * 128 + ((hh * 16) ^ sw));
            bf16x8 kf1 = *(const bf16x8*)(kb + row * 128 + ((64 + hh * 16) ^ sw));
            f32x4 z = (f32x4){0.f, 0.f, 0.f, 0.f};
            z = __builtin_amdgcn_mfma_f32_16x16x32_bf16(kf0, qf0, z, 0, 0, 0);
            sacc[m] = __builtin_amdgcn_mfma_f32_16x16x32_bf16(kf1, qf1, z, 0, 0, 0);
        }
        __builtin_amdgcn_s_setprio(0);

        // softmax on raw scores; scale folded into exp2 constant
        const bool diag = (kt == qb);
        float s[16];
        #pragma unroll
        for (int m = 0; m < 4; m++)
            #pragma unroll
            for (int j = 0; j < 4; j++) {
                float sv = sacc[m][j];
                if (diag) {
                    int klocal = m * 16 + hh * 4 + j;
                    if (klocal > w * 16 + c) sv = -1e30f;
                }
                s[m * 4 + j] = sv;
            }
        // tree max over 16
        float x0 = fmaxf(s[0], s[1]),  x1 = fmaxf(s[2], s[3]);
        float x2 = fmaxf(s[4], s[5]),  x3 = fmaxf(s[6], s[7]);
        float x4 = fmaxf(s[8], s[9]),  x5 = fmaxf(s[10], s[11]);
        float x6 = fmaxf(s[12], s[13]), x7 = fmaxf(s[14], s[15]);
        float y0 = fmaxf(x0, x1), y1 = fmaxf(x2, x3);
        float y2 = fmaxf(x4, x5), y3 = fmaxf(x6, x7);
        float pmax = fmaxf(fmaxf(y0, y1), fmaxf(y2, y3));
        pmax = fmaxf(pmax, __shfl_xor(pmax, 16));
        pmax = fmaxf(pmax, __shfl_xor(pmax, 32));

        // defer-max: rescale only if some row's max grew by > 64 raw (=8 scaled)
        if (!__all(pmax <= m_run + 64.0f)) {
            const float mnew = fmaxf(m_run, pmax);
            const float alpha = exp2f((m_run - mnew) * Cc);
            m_run = mnew;
            l *= alpha;
            const float a0 = __shfl(alpha, hh * 4 + 0);
            const float a1 = __shfl(alpha, hh * 4 + 1);
            const float a2 = __shfl(alpha, hh * 4 + 2);
            const float a3 = __shfl(alpha, hh * 4 + 3);
            #pragma unroll
            for (int n = 0; n < 4; n++) {
                acc_o[n][0] *= a0; acc_o[n][1] *= a1;
                acc_o[n][2] *= a2; acc_o[n][3] *= a3;
            }
        }
        const float mc = m_run * Cc;
        float p[16];
        #pragma unroll
        for (int i = 0; i < 16; i++)
            p[i] = exp2f(fmaf(s[i], Cc, -mc));
        // tree sum into l
        {
            float a0 = p[0] + p[1],  a1 = p[2] + p[3];
            float a2 = p[4] + p[5],  a3 = p[6] + p[7];
            float a4 = p[8] + p[9],  a5 = p[10] + p[11];
            float a6 = p[12] + p[13], a7 = p[14] + p[15];
            float b0 = a0 + a1, b1 = a2 + a3, b2 = a4 + a5, b3 = a6 + a7;
            l += (b0 + b1) + (b2 + b3);
        }

        // pack P -> bf16 via v_cvt_pk_bf16_f32, per-wave swizzled LDS
        {
            char* pb = (char*)&Pls[w][0] + c * 128;
            const int swp = (c & 7) << 4;
            #pragma unroll
            for (int m = 0; m < 4; m++) {
                uint2 u2;
                u2.x = cvtpk_bf16(p[m * 4 + 0], p[m * 4 + 1]);
                u2.y = cvtpk_bf16(p[m * 4 + 2], p[m * 4 + 3]);
                *(uint2*)(pb + ((m * 32 + hh * 8) ^ swp)) = u2;
            }
        }

        // PV: out[q][d], A = P, B = Vt
        {
            const char* pb = (const char*)&Pls[w][0] + c * 128;
            const int swp = (c & 7) << 4;
            bf16x8 pf0 = *(const bf16x8*)(pb + ((hh * 16) ^ swp));
            bf16x8 pf1 = *(const bf16x8*)(pb + ((64 + hh * 16) ^ swp));
            __builtin_amdgcn_s_setprio(1);
            #pragma unroll
            for (int n = 0; n < 4; n++) {
                const int row = n * 16 + c;
                const int sw = (row & 7) << 4;
                bf16x8 vf0 = *(const bf16x8*)(vb + row * 128 + ((hh * 16) ^ sw));
                bf16x8 vf1 = *(const bf16x8*)(vb + row * 128 + ((64 + hh * 16) ^ sw));
                acc_o[n] = __builtin_amdgcn_mfma_f32_16x16x32_bf16(pf0, vf0, acc_o[n], 0, 0, 0);
                acc_o[n] = __builtin_amdgcn_mfma_f32_16x16x32_bf16(pf1, vf1, acc_o[n], 0, 0, 0);
            }
            __builtin_amdgcn_s_setprio(0);
        }
        __syncthreads();
    }
    #undef STAGE

    // final normalization + store
    l += __shfl_xor(l, 16);
    l += __shfl_xor(l, 32);
    const float linv = 1.f / l;
    const float li0 = __shfl(linv, hh * 4 + 0);
    const float li1 = __shfl(linv, hh * 4 + 1);
    const float li2 = __shfl(linv, hh * 4 + 2);
    const float li3 = __shfl(linv, hh * 4 + 3);
    const size_t orow0 = (size_t)(b * SEQ + qb * 64 + w * 16 + hh * 4);
    #pragma unroll
    for (int n = 0; n < 4; n++) {
        const int col = h * HDIM + n * 16 + c;
        a_out[(orow0 + 0) * NSTATE + col] = f2bf(acc_o[n][0] * li0);
        a_out[(orow0 + 1) * NSTATE + col] = f2bf(acc_o[n][1] * li1);
        a_out[(orow0 + 2) * NSTATE + col] = f2bf(acc_o[n][2] * li2);
        a_out[(orow0 + 3) * NSTATE + col] = f2bf(acc_o[n][3] * li3);
    }
}

extern "C" void kernel_launch(void* const* d_in, const int* in_sizes, int n_in,
                              void* d_out, int out_size, void* d_ws, size_t ws_size,
                              hipStream_t stream)
{
    const float* x   = (const float*)d_in[0];
    const float* w_c = (const float*)d_in[1];
    const float* b_c = (const float*)d_in[2];
    const float* w_p = (const float*)d_in[3];
    const float* b_p = (const float*)d_in[4];
    float* out = (float*)d_out;

    const int M = BATCH * SEQ;   // 4096

    char* ws = (char*)d_ws;
    unsigned short* qkvbf = (unsigned short*)ws;                          // 25165824 B
    unsigned short* vt    = (unsigned short*)(ws + 25165824);             //  8388608 B
    unsigned short* xbf   = (unsigned short*)(ws + 25165824 + 8388608);   //  8388608 B (reused as attn_out)
    unsigned short* wcT   = (unsigned short*)(ws + 25165824 + 2*8388608); //  6291456 B
    unsigned short* wpT   = (unsigned short*)(ws + 25165824 + 2*8388608 + 6291456); // 2097152 B

    // fused prep: cast x + transpose-cast w_c, w_p
    prep_kernel<<<5120, 256, 0, stream>>>(x, w_c, w_p, xbf, wcT, wpT);

    // 1) QKV projection -> bf16 qkv   (grid 32x24 = 768, XCD regions 8x12)
    gemm_bf16<8, 12, 32, true><<<768, 256, 0, stream>>>(
        xbf, wcT, b_c, qkvbf, M, 3 * NSTATE, NX);

    // 1b) transpose V -> vt
    vtrans_kernel<<<dim3(SEQ / 64, BATCH * NHEAD), 256, 0, stream>>>(qkvbf, vt);

    // 2) MFMA flash attention (1024 one-tile blocks, 4 blocks/CU, balanced map)
    attn_mfma<<<1024, 256, 0, stream>>>(qkvbf, vt, xbf);

    // 3) output projection -> fp32 d_out  (64x64 tiles, BK=64, grid 64x16=1024,
    //    XCD regions 16x8)
    gemm_bf16_s<16, 8, 64, false><<<1024, 256, 0, stream>>>(
        xbf, wpT, b_p, out, M, NSTATE, NX);
}